// Round 1
// baseline (41.741 us; speedup 1.0000x reference)
//
#include <hip/hip_runtime.h>
#include <math.h>

#define BB 2
#define CC 16
#define HH 32
#define WW 32
#define NN (HH*WW)

// ---------------------------------------------------------------------------
// Kernel 1: per-(b,k) precompute.
//   kd[(b*N+k)*12] = { X, Y, Z, pjr0, pjr1, pjr2, w0, w1, w2, 0, 0, 0 }
//     xyz   = unprojected point (camera frame)
//     pjr   = pie(T_k @ xyz_k) + revisions_k   (the per-k residual target)
//     w     = per-channel weights
//   et[(b*N+k)*16] = embeddings transposed to (B,N,C) for float4 loads.
// ---------------------------------------------------------------------------
__global__ __launch_bounds__(256)
void dse3_prep(const float* __restrict__ emb,
               const float* __restrict__ rev,
               const float* __restrict__ wgt,
               const float* __restrict__ dep,
               const float* __restrict__ pix,
               const float* __restrict__ Tm,
               float* __restrict__ kd,
               float* __restrict__ et)
{
    int idx = blockIdx.x * 256 + threadIdx.x;
    if (idx >= BB * NN) return;
    int b = idx / NN;
    int k = idx - b * NN;

    float fx = pix[b*16 + 0], fy = pix[b*16 + 5];
    float x0 = pix[b*16 + 2], y0 = pix[b*16 + 6];

    float u = (float)(k & (WW - 1));   // column (x)
    float v = (float)(k >> 5);         // row (y), W==32
    float z = dep[b*NN + k];
    float X = (u - x0) * z / fx;
    float Y = (v - y0) * z / fy;

    const float* T = Tm + (size_t)idx * 16;
    float Tx = T[0]*X + T[1]*Y + T[2]*z  + T[3];
    float Ty = T[4]*X + T[5]*Y + T[6]*z  + T[7];
    float Tz = T[8]*X + T[9]*Y + T[10]*z + T[11];
    float di = 1.0f / Tz;

    float p0 = fx*Tx*di + x0 + rev[(size_t)b*3*NN + 0*NN + k];
    float p1 = fy*Ty*di + y0 + rev[(size_t)b*3*NN + 1*NN + k];
    float p2 = di            + rev[(size_t)b*3*NN + 2*NN + k];
    float w0 = wgt[(size_t)b*3*NN + 0*NN + k];
    float w1 = wgt[(size_t)b*3*NN + 1*NN + k];
    float w2 = wgt[(size_t)b*3*NN + 2*NN + k];

    float4* kp = (float4*)(kd + (size_t)idx * 12);
    kp[0] = make_float4(X, Y, z, p0);
    kp[1] = make_float4(p1, p2, w0, w1);
    kp[2] = make_float4(w2, 0.f, 0.f, 0.f);

    float4* ep = (float4*)(et + (size_t)idx * 16);
    #pragma unroll
    for (int c4 = 0; c4 < 4; ++c4) {
        float4 val;
        val.x = emb[(size_t)b*CC*NN + (size_t)(c4*4 + 0)*NN + k];
        val.y = emb[(size_t)b*CC*NN + (size_t)(c4*4 + 1)*NN + k];
        val.z = emb[(size_t)b*CC*NN + (size_t)(c4*4 + 2)*NN + k];
        val.w = emb[(size_t)b*CC*NN + (size_t)(c4*4 + 3)*NN + k];
        ep[c4] = val;
    }
}

// ---------------------------------------------------------------------------
// Kernel 2: one wave (64 lanes) per output pixel i. Lanes stride over k.
// Accumulate 6x6 symmetric H (21) + rhs (6), wave-reduce, lane 0 solves
// (double Cholesky, fully unrolled -> registers), expmap, compose with Tmat.
// ---------------------------------------------------------------------------
__global__ __launch_bounds__(256)
void dse3_main(const float* __restrict__ kd,
               const float* __restrict__ et,
               const float* __restrict__ pix,
               const float* __restrict__ Tm,
               float* __restrict__ out)
{
    int wid  = blockIdx.x * 4 + (threadIdx.x >> 6);   // global wave id = b*N + i
    int lane = threadIdx.x & 63;
    int b = wid / NN;

    float fx = pix[b*16 + 0], fy = pix[b*16 + 5];
    float x0 = pix[b*16 + 2], y0 = pix[b*16 + 6];

    // per-i embedding (broadcast load, L2/L1-resident)
    float ei[16];
    {
        const float4* ep = (const float4*)(et + (size_t)wid * 16);
        #pragma unroll
        for (int c4 = 0; c4 < 4; ++c4) {
            float4 v4 = ep[c4];
            ei[c4*4+0] = v4.x; ei[c4*4+1] = v4.y;
            ei[c4*4+2] = v4.z; ei[c4*4+3] = v4.w;
        }
    }
    const float* Ti = Tm + (size_t)wid * 16;
    float R00=Ti[0], R01=Ti[1], R02=Ti[2],  t0=Ti[3];
    float R10=Ti[4], R11=Ti[5], R12=Ti[6],  t1=Ti[7];
    float R20=Ti[8], R21=Ti[9], R22=Ti[10], t2=Ti[11];

    float Hm[21];
    float rh[6];
    #pragma unroll
    for (int t = 0; t < 21; ++t) Hm[t] = 0.f;
    #pragma unroll
    for (int t = 0; t < 6; ++t)  rh[t] = 0.f;

    int kbase = b * NN;
    for (int k0 = 0; k0 < NN/64; ++k0) {
        int kb = kbase + k0*64 + lane;

        // affinity: exp(-||e_i - e_k||)
        float ssq = 0.f;
        {
            const float4* ep = (const float4*)(et + (size_t)kb * 16);
            #pragma unroll
            for (int c4 = 0; c4 < 4; ++c4) {
                float4 v4 = ep[c4];
                float d0 = v4.x - ei[c4*4+0];
                float d1 = v4.y - ei[c4*4+1];
                float d2 = v4.z - ei[c4*4+2];
                float d3 = v4.w - ei[c4*4+3];
                ssq += d0*d0 + d1*d1 + d2*d2 + d3*d3;
            }
        }
        float aff = __expf(-sqrtf(ssq));

        const float4* kp = (const float4*)(kd + (size_t)kb * 12);
        float4 q0 = kp[0], q1 = kp[1], q2 = kp[2];
        float X = q0.x, Y = q0.y, Z = q0.z;

        // TiXj = R_i xyz_k + t_i
        float Tx = R00*X + R01*Y + R02*Z + t0;
        float Ty = R10*X + R11*Y + R12*Z + t1;
        float Tz = R20*X + R21*Y + R22*Z + t2;
        float di = 1.0f / Tz;

        float uu = fx*Tx*di + x0;
        float vv = fy*Ty*di + y0;
        float r0 = uu - q0.w;
        float r1 = vv - q1.x;
        float r2 = di - q1.y;

        float dd = di*di;
        float aJ =  fx*di;
        float cJ = -fx*Tx*dd;
        float eJ =  fy*di;
        float fJ = -fy*Ty*dd;
        float gJ = -dd;

        // Jac = Jp @ [I3 | hat(xyz_k)]  (3x6, structural zeros const-folded)
        float J0[6] = { aJ, 0.f, cJ, -cJ*Y,       cJ*X - aJ*Z,  aJ*Y };
        float J1[6] = { 0.f, eJ, fJ,  eJ*Z - fJ*Y, fJ*X,       -eJ*X };
        float J2[6] = { 0.f, 0.f, gJ, -gJ*Y,       gJ*X,        0.f  };

        #pragma unroll
        for (int p = 0; p < 6; ++p)
            rh[p] += J0[p]*r0 + J1[p]*r1 + J2[p]*r2;

        float ww0 = aff*q1.z, ww1 = aff*q1.w, ww2 = aff*q2.x;
        int ix = 0;
        #pragma unroll
        for (int p = 0; p < 6; ++p) {
            float a0 = ww0*J0[p], a1 = ww1*J1[p], a2 = ww2*J2[p];
            #pragma unroll
            for (int q = p; q < 6; ++q)
                Hm[ix++] += a0*J0[q] + a1*J1[q] + a2*J2[q];
        }
    }

    // wave butterfly reduce (27 values)
    #pragma unroll
    for (int off = 32; off > 0; off >>= 1) {
        #pragma unroll
        for (int t = 0; t < 21; ++t) Hm[t] += __shfl_xor(Hm[t], off, 64);
        #pragma unroll
        for (int t = 0; t < 6; ++t)  rh[t] += __shfl_xor(rh[t], off, 64);
    }
    if (lane != 0) return;

    // ---- 6x6 solve: double Cholesky, fully unrolled (static indexing) ----
    double am[6][6];
    {
        int ix = 0;
        #pragma unroll
        for (int p = 0; p < 6; ++p)
            #pragma unroll
            for (int q = p; q < 6; ++q) {
                am[p][q] = (double)Hm[ix];
                am[q][p] = (double)Hm[ix];
                ++ix;
            }
    }
    double L[6][6];
    #pragma unroll
    for (int p = 0; p < 6; ++p) {
        #pragma unroll
        for (int q = 0; q <= p; ++q) {
            double s = am[p][q];
            #pragma unroll
            for (int r = 0; r < q; ++r) s -= L[p][r]*L[q][r];
            if (q == p) L[p][p] = sqrt(s);
            else        L[p][q] = s / L[q][q];
        }
    }
    double yv[6];
    #pragma unroll
    for (int p = 0; p < 6; ++p) {
        double s = (double)rh[p];
        #pragma unroll
        for (int r = 0; r < p; ++r) s -= L[p][r]*yv[r];
        yv[p] = s / L[p][p];
    }
    double sol[6];
    #pragma unroll
    for (int pi = 5; pi >= 0; --pi) {
        double s = yv[pi];
        #pragma unroll
        for (int r = pi + 1; r < 6; ++r) s -= L[r][pi]*sol[r];
        sol[pi] = s / L[pi][pi];
    }

    // ---- expmap(delta) ----
    double vx = sol[0], vy = sol[1], vz = sol[2];
    double wx = sol[3], wy = sol[4], wz = sol[5];
    double th2 = wx*wx + wy*wy + wz*wz;
    double th  = sqrt(th2);
    double Ae, Be, Ce;
    if (th < 1e-4) {
        Ae = 1.0 - th2/6.0;
        Be = 0.5 - th2/24.0;
        Ce = 1.0/6.0 - th2/120.0;
    } else {
        double sn = sin(th), cn = cos(th);
        Ae = sn/th;
        Be = (1.0 - cn)/th2;
        Ce = (th - sn)/(th2*th);
    }
    double Wh[3][3] = {{0.0,-wz, wy},{ wz,0.0,-wx},{-wy, wx,0.0}};
    double W2[3][3] = {{wx*wx - th2, wx*wy,       wx*wz      },
                       {wx*wy,       wy*wy - th2, wy*wz      },
                       {wx*wz,       wy*wz,       wz*wz - th2}};
    double Rd[3][3], Vd[3][3];
    #pragma unroll
    for (int p = 0; p < 3; ++p)
        #pragma unroll
        for (int q = 0; q < 3; ++q) {
            double idq = (p == q) ? 1.0 : 0.0;
            Rd[p][q] = idq + Ae*Wh[p][q] + Be*W2[p][q];
            Vd[p][q] = idq + Be*Wh[p][q] + Ce*W2[p][q];
        }
    double td[3];
    #pragma unroll
    for (int p = 0; p < 3; ++p)
        td[p] = Vd[p][0]*vx + Vd[p][1]*vy + Vd[p][2]*vz;

    // ---- out = dT @ Tmat_i ----
    float* o = out + (size_t)wid * 16;
    #pragma unroll
    for (int p = 0; p < 3; ++p) {
        #pragma unroll
        for (int q = 0; q < 4; ++q) {
            double s = Rd[p][0]*(double)Ti[q]
                     + Rd[p][1]*(double)Ti[4 + q]
                     + Rd[p][2]*(double)Ti[8 + q]
                     + td[p]   *(double)Ti[12 + q];
            o[p*4 + q] = (float)s;
        }
    }
    #pragma unroll
    for (int q = 0; q < 4; ++q) o[12 + q] = Ti[12 + q];
}

extern "C" void kernel_launch(void* const* d_in, const int* in_sizes, int n_in,
                              void* d_out, int out_size, void* d_ws, size_t ws_size,
                              hipStream_t stream) {
    const float* emb = (const float*)d_in[0];  // (B,C,H,W)
    const float* rev = (const float*)d_in[1];  // (B,3,H,W)
    const float* wgt = (const float*)d_in[2];  // (B,3,H,W)
    const float* dep = (const float*)d_in[3];  // (B,1,H,W)
    const float* pix = (const float*)d_in[4];  // (B,4,4)
    const float* Tm  = (const float*)d_in[5];  // (B,H,W,4,4)
    float* out = (float*)d_out;                // (B,H,W,4,4)

    float* kd = (float*)d_ws;                       // (B*N,12) = 98304 B
    float* et = kd + (size_t)BB*NN*12;              // (B*N,16) = 131072 B

    dse3_prep<<<(BB*NN + 255)/256, 256, 0, stream>>>(emb, rev, wgt, dep, pix, Tm, kd, et);
    dse3_main<<<(BB*NN)/4, 256, 0, stream>>>(kd, et, pix, Tm, out);
}

// Round 2
// 39.629 us; speedup vs baseline: 1.0533x; 1.0533x over previous
//
#include <hip/hip_runtime.h>
#include <math.h>

#define BB 2
#define CC 16
#define HH 32
#define WW 32
#define NN (HH*WW)

// ---------------------------------------------------------------------------
// Kernel 1: per-(b,k) precompute.
//   kd[(b*N+k)*12] = { X, Y, Z, pjr0, pjr1, pjr2, w0, w1, w2(?), se, .. }
//     xyz = unprojected point; pjr = pie(T_k xyz_k) + rev_k; w = weights;
//     se  = |e_k|^2 (for Gram-trick affinity)
//   et[(b*N+k)*16] = embeddings transposed to (B,N,C) for float4 loads.
// ---------------------------------------------------------------------------
__global__ __launch_bounds__(256)
void dse3_prep(const float* __restrict__ emb,
               const float* __restrict__ rev,
               const float* __restrict__ wgt,
               const float* __restrict__ dep,
               const float* __restrict__ pix,
               const float* __restrict__ Tm,
               float* __restrict__ kd,
               float* __restrict__ et)
{
    int idx = blockIdx.x * 256 + threadIdx.x;
    if (idx >= BB * NN) return;
    int b = idx / NN;
    int k = idx - b * NN;

    float fx = pix[b*16 + 0], fy = pix[b*16 + 5];
    float x0 = pix[b*16 + 2], y0 = pix[b*16 + 6];

    float u = (float)(k & (WW - 1));
    float v = (float)(k >> 5);
    float z = dep[b*NN + k];
    float X = (u - x0) * z / fx;
    float Y = (v - y0) * z / fy;

    const float* T = Tm + (size_t)idx * 16;
    float Tx = T[0]*X + T[1]*Y + T[2]*z  + T[3];
    float Ty = T[4]*X + T[5]*Y + T[6]*z  + T[7];
    float Tz = T[8]*X + T[9]*Y + T[10]*z + T[11];
    float di = 1.0f / Tz;

    float p0 = fx*Tx*di + x0 + rev[(size_t)b*3*NN + 0*NN + k];
    float p1 = fy*Ty*di + y0 + rev[(size_t)b*3*NN + 1*NN + k];
    float p2 = di            + rev[(size_t)b*3*NN + 2*NN + k];
    float w0 = wgt[(size_t)b*3*NN + 0*NN + k];
    float w1 = wgt[(size_t)b*3*NN + 1*NN + k];
    float w2 = wgt[(size_t)b*3*NN + 2*NN + k];

    // embeddings transpose + |e|^2
    float se = 0.f;
    float ev[16];
    #pragma unroll
    for (int c = 0; c < 16; ++c) {
        ev[c] = emb[(size_t)b*CC*NN + (size_t)c*NN + k];
        se += ev[c]*ev[c];
    }
    float4* ep = (float4*)(et + (size_t)idx * 16);
    #pragma unroll
    for (int c4 = 0; c4 < 4; ++c4)
        ep[c4] = make_float4(ev[c4*4+0], ev[c4*4+1], ev[c4*4+2], ev[c4*4+3]);

    float4* kp = (float4*)(kd + (size_t)idx * 12);
    kp[0] = make_float4(X, Y, z, p0);
    kp[1] = make_float4(p1, p2, w0, w1);
    kp[2] = make_float4(w2, se, 0.f, 0.f);
}

// ---------------------------------------------------------------------------
// Kernel 2: one block (4 waves, 256 thr) per output pixel i.
// Thread t handles k = j*256 + t (j=0..3). Accumulate 27 floats, wave
// butterfly, cross-wave LDS reduce, store to hws[pix*27 + t].
// ---------------------------------------------------------------------------
__global__ __launch_bounds__(256)
void dse3_accum(const float* __restrict__ kd,
                const float* __restrict__ et,
                const float* __restrict__ pix,
                float* __restrict__ hws)
{
    __shared__ float lds[4][27];
    int wid  = blockIdx.x;            // pixel id = b*N + i
    int tid  = threadIdx.x;
    int lane = tid & 63;
    int wv   = tid >> 6;
    int b = wid / NN;

    float fx = pix[b*16 + 0], fy = pix[b*16 + 5];
    float x0 = pix[b*16 + 2], y0 = pix[b*16 + 6];

    // per-i data (broadcast, L1/L2-resident)
    float ei[16];
    float sei;
    {
        const float4* ep = (const float4*)(et + (size_t)wid * 16);
        #pragma unroll
        for (int c4 = 0; c4 < 4; ++c4) {
            float4 v4 = ep[c4];
            ei[c4*4+0] = v4.x; ei[c4*4+1] = v4.y;
            ei[c4*4+2] = v4.z; ei[c4*4+3] = v4.w;
        }
        const float4* kp = (const float4*)(kd + (size_t)wid * 12);
        sei = kp[2].y;
    }
    // rotation row-major + translation of T_i: read from kd? No — need Tm.
    // We stash R,t in registers by reloading from the original Tm via pix?
    // Simpler: Ti passed via kd is not stored; load from Tm-equivalent:
    // we recompute from kd? Not possible — so Tm is passed separately below.
    // (see dse3_accum2 signature change)
    (void)lds; (void)lane; (void)wv; (void)fx; (void)fy; (void)x0; (void)y0;
    (void)ei; (void)sei; (void)hws;
}

// Actual accumulate kernel (with Tm).
__global__ __launch_bounds__(256)
void dse3_accum2(const float* __restrict__ kd,
                 const float* __restrict__ et,
                 const float* __restrict__ pix,
                 const float* __restrict__ Tm,
                 float* __restrict__ hws)
{
    __shared__ float lds[4][27];
    int wid  = blockIdx.x;            // pixel id = b*N + i
    int tid  = threadIdx.x;
    int wv   = tid >> 6;
    int b = wid / NN;

    float fx = pix[b*16 + 0], fy = pix[b*16 + 5];
    float x0 = pix[b*16 + 2], y0 = pix[b*16 + 6];

    float ei[16];
    {
        const float4* ep = (const float4*)(et + (size_t)wid * 16);
        #pragma unroll
        for (int c4 = 0; c4 < 4; ++c4) {
            float4 v4 = ep[c4];
            ei[c4*4+0] = v4.x; ei[c4*4+1] = v4.y;
            ei[c4*4+2] = v4.z; ei[c4*4+3] = v4.w;
        }
    }
    float sei = kd[(size_t)wid*12 + 9];

    const float* Ti = Tm + (size_t)wid * 16;
    float R00=Ti[0], R01=Ti[1], R02=Ti[2],  t0=Ti[3];
    float R10=Ti[4], R11=Ti[5], R12=Ti[6],  t1=Ti[7];
    float R20=Ti[8], R21=Ti[9], R22=Ti[10], t2=Ti[11];

    float acc[27];
    #pragma unroll
    for (int t = 0; t < 27; ++t) acc[t] = 0.f;

    int kbase = b * NN;
    #pragma unroll
    for (int j = 0; j < 4; ++j) {
        int kb = kbase + j*256 + tid;

        // affinity via Gram trick: ||ei-ek||^2 = sei + sek - 2 ei.ek
        float dot = 0.f;
        {
            const float4* ep = (const float4*)(et + (size_t)kb * 16);
            #pragma unroll
            for (int c4 = 0; c4 < 4; ++c4) {
                float4 v4 = ep[c4];
                dot += v4.x*ei[c4*4+0] + v4.y*ei[c4*4+1]
                     + v4.z*ei[c4*4+2] + v4.w*ei[c4*4+3];
            }
        }
        const float4* kp = (const float4*)(kd + (size_t)kb * 12);
        float4 q0 = kp[0], q1 = kp[1], q2 = kp[2];
        float ssq = fmaxf(sei + q2.y - 2.f*dot, 0.f);
        float aff = __expf(-sqrtf(ssq));

        float X = q0.x, Y = q0.y, Z = q0.z;
        float Tx = R00*X + R01*Y + R02*Z + t0;
        float Ty = R10*X + R11*Y + R12*Z + t1;
        float Tz = R20*X + R21*Y + R22*Z + t2;
        float di = 1.0f / Tz;

        float r0 = fx*Tx*di + x0 - q0.w;
        float r1 = fy*Ty*di + y0 - q1.x;
        float r2 = di            - q1.y;

        float dd = di*di;
        float aJ =  fx*di;
        float cJ = -fx*Tx*dd;
        float eJ =  fy*di;
        float fJ = -fy*Ty*dd;
        float gJ = -dd;

        float J0[6] = { aJ, 0.f, cJ, -cJ*Y,        cJ*X - aJ*Z,  aJ*Y };
        float J1[6] = { 0.f, eJ, fJ,  eJ*Z - fJ*Y, fJ*X,        -eJ*X };
        float J2[6] = { 0.f, 0.f, gJ, -gJ*Y,       gJ*X,         0.f  };

        #pragma unroll
        for (int p = 0; p < 6; ++p)
            acc[21 + p] += J0[p]*r0 + J1[p]*r1 + J2[p]*r2;

        float ww0 = aff*q1.z, ww1 = aff*q1.w, ww2 = aff*q2.x;
        int ix = 0;
        #pragma unroll
        for (int p = 0; p < 6; ++p) {
            float a0 = ww0*J0[p], a1 = ww1*J1[p], a2 = ww2*J2[p];
            #pragma unroll
            for (int q = p; q < 6; ++q) {
                acc[ix] += a0*J0[q] + a1*J1[q] + a2*J2[q];
                ++ix;
            }
        }
    }

    // wave butterfly (full 64-lane sum, result in all lanes)
    #pragma unroll
    for (int off = 32; off > 0; off >>= 1)
        #pragma unroll
        for (int t = 0; t < 27; ++t)
            acc[t] += __shfl_xor(acc[t], off, 64);

    if ((tid & 63) == 0)
        #pragma unroll
        for (int t = 0; t < 27; ++t) lds[wv][t] = acc[t];
    __syncthreads();

    if (tid < 27)
        hws[(size_t)wid*27 + tid] =
            lds[0][tid] + lds[1][tid] + lds[2][tid] + lds[3][tid];
}

// ---------------------------------------------------------------------------
// Kernel 3: one THREAD per pixel — 6x6 double Cholesky solve, expmap,
// compose with Tmat. 2048 threads total; full lane utilization.
// ---------------------------------------------------------------------------
__global__ __launch_bounds__(256)
void dse3_solve(const float* __restrict__ hws,
                const float* __restrict__ Tm,
                float* __restrict__ out)
{
    int p_ix = blockIdx.x * 256 + threadIdx.x;
    if (p_ix >= BB * NN) return;

    const float* Hf = hws + (size_t)p_ix * 27;
    float Hm[21], rh[6];
    #pragma unroll
    for (int t = 0; t < 21; ++t) Hm[t] = Hf[t];
    #pragma unroll
    for (int t = 0; t < 6; ++t)  rh[t] = Hf[21 + t];

    double am[6][6];
    {
        int ix = 0;
        #pragma unroll
        for (int p = 0; p < 6; ++p)
            #pragma unroll
            for (int q = p; q < 6; ++q) {
                am[p][q] = (double)Hm[ix];
                am[q][p] = (double)Hm[ix];
                ++ix;
            }
    }
    double L[6][6];
    #pragma unroll
    for (int p = 0; p < 6; ++p) {
        #pragma unroll
        for (int q = 0; q <= p; ++q) {
            double s = am[p][q];
            #pragma unroll
            for (int r = 0; r < q; ++r) s -= L[p][r]*L[q][r];
            if (q == p) L[p][p] = sqrt(s);
            else        L[p][q] = s / L[q][q];
        }
    }
    double yv[6];
    #pragma unroll
    for (int p = 0; p < 6; ++p) {
        double s = (double)rh[p];
        #pragma unroll
        for (int r = 0; r < p; ++r) s -= L[p][r]*yv[r];
        yv[p] = s / L[p][p];
    }
    double sol[6];
    #pragma unroll
    for (int pi = 5; pi >= 0; --pi) {
        double s = yv[pi];
        #pragma unroll
        for (int r = pi + 1; r < 6; ++r) s -= L[r][pi]*sol[r];
        sol[pi] = s / L[pi][pi];
    }

    double vx = sol[0], vy = sol[1], vz = sol[2];
    double wx = sol[3], wy = sol[4], wz = sol[5];
    double th2 = wx*wx + wy*wy + wz*wz;
    double th  = sqrt(th2);
    double Ae, Be, Ce;
    if (th < 1e-4) {
        Ae = 1.0 - th2/6.0;
        Be = 0.5 - th2/24.0;
        Ce = 1.0/6.0 - th2/120.0;
    } else {
        double sn = sin(th), cn = cos(th);
        Ae = sn/th;
        Be = (1.0 - cn)/th2;
        Ce = (th - sn)/(th2*th);
    }
    double Wh[3][3] = {{0.0,-wz, wy},{ wz,0.0,-wx},{-wy, wx,0.0}};
    double W2[3][3] = {{wx*wx - th2, wx*wy,       wx*wz      },
                       {wx*wy,       wy*wy - th2, wy*wz      },
                       {wx*wz,       wy*wz,       wz*wz - th2}};
    double Rd[3][3], Vd[3][3];
    #pragma unroll
    for (int p = 0; p < 3; ++p)
        #pragma unroll
        for (int q = 0; q < 3; ++q) {
            double idq = (p == q) ? 1.0 : 0.0;
            Rd[p][q] = idq + Ae*Wh[p][q] + Be*W2[p][q];
            Vd[p][q] = idq + Be*Wh[p][q] + Ce*W2[p][q];
        }
    double td[3];
    #pragma unroll
    for (int p = 0; p < 3; ++p)
        td[p] = Vd[p][0]*vx + Vd[p][1]*vy + Vd[p][2]*vz;

    const float* Ti = Tm + (size_t)p_ix * 16;
    float* o = out + (size_t)p_ix * 16;
    #pragma unroll
    for (int p = 0; p < 3; ++p) {
        #pragma unroll
        for (int q = 0; q < 4; ++q) {
            double s = Rd[p][0]*(double)Ti[q]
                     + Rd[p][1]*(double)Ti[4 + q]
                     + Rd[p][2]*(double)Ti[8 + q]
                     + td[p]   *(double)Ti[12 + q];
            o[p*4 + q] = (float)s;
        }
    }
    #pragma unroll
    for (int q = 0; q < 4; ++q) o[12 + q] = Ti[12 + q];
}

extern "C" void kernel_launch(void* const* d_in, const int* in_sizes, int n_in,
                              void* d_out, int out_size, void* d_ws, size_t ws_size,
                              hipStream_t stream) {
    const float* emb = (const float*)d_in[0];  // (B,C,H,W)
    const float* rev = (const float*)d_in[1];  // (B,3,H,W)
    const float* wgt = (const float*)d_in[2];  // (B,3,H,W)
    const float* dep = (const float*)d_in[3];  // (B,1,H,W)
    const float* pix = (const float*)d_in[4];  // (B,4,4)
    const float* Tm  = (const float*)d_in[5];  // (B,H,W,4,4)
    float* out = (float*)d_out;                // (B,H,W,4,4)

    float* kd  = (float*)d_ws;                       // (B*N,12)
    float* et  = kd + (size_t)BB*NN*12;              // (B*N,16)
    float* hws = et + (size_t)BB*NN*16;              // (B*N,27)

    dse3_prep<<<(BB*NN + 255)/256, 256, 0, stream>>>(emb, rev, wgt, dep, pix, Tm, kd, et);
    dse3_accum2<<<BB*NN, 256, 0, stream>>>(kd, et, pix, Tm, hws);
    dse3_solve<<<(BB*NN + 255)/256, 256, 0, stream>>>(hws, Tm, out);
}